// Round 9
// baseline (179.924 us; speedup 1.0000x reference)
//
#include <hip/hip_runtime.h>
#include <hip/hip_bf16.h>

#define N_NODES 50000
#define N_EDGES 800000
#define IN_DIM 128
#define OUT_DIM 64
#define NEG_SLOPE 0.01f
#define NEG_INF (-3.0e38f)

#define N_STRIPS (N_NODES / 16)       // 3125 16-node MFMA strips
#define Z_BLOCKS ((N_STRIPS + 3) / 4) // 782 (4 waves/block, 1 strip/wave)
#define E_I4 (N_EDGES / 4)            // 200000
#define EDGE_BLOCKS ((E_I4 + 255) / 256)

// bucket sort params: 128 nodes/bucket, 4 cursor replicas (64B-padded)
#define NB ((N_NODES + 127) / 128)    // 391 buckets
#define CAP_R 768                      // capacity per (bucket, replica)
#define CAP_B (CAP_R * 4)              // 3072 per bucket (mean 2046)
#define CNT_STRIDE 16                  // ints; one 64B line per counter

typedef __bf16 bf16x8 __attribute__((ext_vector_type(8)));
typedef float f32x4 __attribute__((ext_vector_type(4)));

__device__ __forceinline__ float rlanef(float v, int l) {
  return __uint_as_float(__builtin_amdgcn_readlane(__float_as_uint(v), l));
}
__device__ __forceinline__ int rlanei(int v, int l) {
  return __builtin_amdgcn_readlane(v, l);
}

__device__ __forceinline__ unsigned short f2bf_us(float f) {
  __hip_bfloat16 h = __float2bfloat16(f);  // RNE
  return *reinterpret_cast<unsigned short*>(&h);
}
__device__ __forceinline__ bf16x8 pack_bf16(float4 lo, float4 hi) {
  union { bf16x8 v; unsigned short u[8]; } r;
  r.u[0] = f2bf_us(lo.x); r.u[1] = f2bf_us(lo.y);
  r.u[2] = f2bf_us(lo.z); r.u[3] = f2bf_us(lo.w);
  r.u[4] = f2bf_us(hi.x); r.u[5] = f2bf_us(hi.y);
  r.u[6] = f2bf_us(hi.z); r.u[7] = f2bf_us(hi.w);
  return r.v;
}

// ---------------------------------------------------------------------------
// Stage 1 (fused). Blocks [0, Z_BLOCKS): MFMA z-GEMM (R7 structure).
// Blocks [Z_BLOCKS,...): bucket pass — edge -> bucket dst>>7, hot-line
// atomic cursor (x4 replicas), store packed (localdst<<16 | src).
// ---------------------------------------------------------------------------
__global__ __launch_bounds__(256) void gat_z_bucket(
    const float* __restrict__ feat, const float* __restrict__ fcw,
    const float* __restrict__ attnw, __hip_bfloat16* __restrict__ z,
    float* __restrict__ asrc, float* __restrict__ adst,
    const int* __restrict__ src, const int* __restrict__ dst,
    int* __restrict__ cnt, unsigned* __restrict__ pairs) {
  if (blockIdx.x >= Z_BLOCKS) {
    int t = (blockIdx.x - Z_BLOCKS) * 256 + threadIdx.x;
    if (t < E_I4) {
      int4 s = ((const int4*)src)[t];
      int4 d = ((const int4*)dst)[t];
      const int rep = threadIdx.x & 3;
#define BKT_PUT(dd, ss)                                                    \
  {                                                                        \
    int b = (dd) >> 7;                                                     \
    int r = atomicAdd(cnt + (b * 4 + rep) * CNT_STRIDE, 1);                \
    if (r < CAP_R)                                                         \
      pairs[b * CAP_B + rep * CAP_R + r] =                                 \
          ((unsigned)((dd) & 127) << 16) | (unsigned)(ss);                 \
  }
      BKT_PUT(d.x, s.x)
      BKT_PUT(d.y, s.y)
      BKT_PUT(d.z, s.z)
      BKT_PUT(d.w, s.w)
#undef BKT_PUT
    }
    return;
  }

  const int lane = threadIdx.x & 63;
  const int m = lane & 15;
  const int quad = lane >> 4;
  const int wv = blockIdx.x * 4 + (threadIdx.x >> 6);
  if (wv >= N_STRIPS) return;
  const int n0 = wv * 16;

  bf16x8 bfrag[4][4];
#pragma unroll
  for (int t = 0; t < 4; ++t) {
    const float* wr = fcw + (size_t)(m + 16 * t) * IN_DIM + quad * 8;
#pragma unroll
    for (int c = 0; c < 4; ++c) {
      float4 lo = *(const float4*)(wr + c * 32);
      float4 hi = *(const float4*)(wr + c * 32 + 4);
      bfrag[t][c] = pack_bf16(lo, hi);
    }
  }

  f32x4 acc[4] = {{0.f, 0.f, 0.f, 0.f}, {0.f, 0.f, 0.f, 0.f},
                  {0.f, 0.f, 0.f, 0.f}, {0.f, 0.f, 0.f, 0.f}};
  const float* ar = feat + (size_t)(n0 + m) * IN_DIM + quad * 8;
#pragma unroll
  for (int c = 0; c < 4; ++c) {
    float4 lo = *(const float4*)(ar + c * 32);
    float4 hi = *(const float4*)(ar + c * 32 + 4);
    const bf16x8 af = pack_bf16(lo, hi);
#pragma unroll
    for (int t = 0; t < 4; ++t)
      acc[t] = __builtin_amdgcn_mfma_f32_16x16x32_bf16(af, bfrag[t][c],
                                                       acc[t], 0, 0, 0);
  }

#pragma unroll
  for (int t = 0; t < 4; ++t)
#pragma unroll
    for (int r = 0; r < 4; ++r)
      z[(size_t)(n0 + quad * 4 + r) * OUT_DIM + m + 16 * t] =
          __float2bfloat16(acc[t][r]);

  float aws[4], awd[4];
#pragma unroll
  for (int t = 0; t < 4; ++t) {
    aws[t] = attnw[m + 16 * t];
    awd[t] = attnw[OUT_DIM + m + 16 * t];
  }
  float ps[4], pd[4];
#pragma unroll
  for (int r = 0; r < 4; ++r) {
    float s = 0.f, d = 0.f;
#pragma unroll
    for (int t = 0; t < 4; ++t) {
      s = fmaf(acc[t][r], aws[t], s);
      d = fmaf(acc[t][r], awd[t], d);
    }
    ps[r] = s;
    pd[r] = d;
  }
#pragma unroll
  for (int off = 1; off < 16; off <<= 1) {
#pragma unroll
    for (int r = 0; r < 4; ++r) {
      ps[r] += __shfl_xor(ps[r], off, 64);
      pd[r] += __shfl_xor(pd[r], off, 64);
    }
  }
  if (m == 0) {
#pragma unroll
    for (int r = 0; r < 4; ++r) {
      asrc[n0 + quad * 4 + r] = ps[r];
      adst[n0 + quad * 4 + r] = pd[r];
    }
  }
}

// ---------------------------------------------------------------------------
// Exclusive scan of 391 bucket totals (one block). Also writes sentinel.
// ---------------------------------------------------------------------------
__global__ __launch_bounds__(512) void gat_bucket_scan(
    const int* __restrict__ cnt, int* __restrict__ bbase,
    int* __restrict__ offsets) {
  __shared__ int ps[512];
  const int t = threadIdx.x;
  int tot = 0;
  if (t < NB) {
#pragma unroll
    for (int rep = 0; rep < 4; ++rep) tot += cnt[(t * 4 + rep) * CNT_STRIDE];
  }
  ps[t] = tot;
  __syncthreads();
  for (int off = 1; off < 512; off <<= 1) {
    int u = (t >= off) ? ps[t - off] : 0;
    __syncthreads();
    ps[t] += u;
    __syncthreads();
  }
  if (t < NB) bbase[t] = ps[t] - tot;  // exclusive
  if (t == NB - 1) offsets[N_NODES] = ps[t];  // == N_EDGES
}

// ---------------------------------------------------------------------------
// Per-bucket CSR build: LDS hist over 128 local bins -> LDS scan -> offsets
// + contiguous placement of src into ssorted. No global atomics.
// ---------------------------------------------------------------------------
__global__ __launch_bounds__(256) void gat_build_csr(
    const unsigned* __restrict__ pairs, const int* __restrict__ cnt,
    const int* __restrict__ bbase, int* __restrict__ offsets,
    int* __restrict__ ssorted) {
  __shared__ int hist[128], exo[128], cur[128], scnt[4];
  const int b = blockIdx.x;
  const int tid = threadIdx.x;
  if (tid < 128) hist[tid] = 0;
  if (tid < 4) scnt[tid] = min(cnt[(b * 4 + tid) * CNT_STRIDE], CAP_R);
  __syncthreads();

  const unsigned* bp = pairs + (size_t)b * CAP_B;
#pragma unroll 1
  for (int rep = 0; rep < 4; ++rep) {
    const int c = scnt[rep];
    for (int i = tid; i < c; i += 256)
      atomicAdd(&hist[bp[rep * CAP_R + i] >> 16], 1);
  }
  __syncthreads();

  // inclusive Hillis-Steele over 128, then exclusive = incl - hist
  if (tid < 128) exo[tid] = hist[tid];
  __syncthreads();
  for (int off = 1; off < 128; off <<= 1) {
    int u = (tid >= off && tid < 128) ? exo[tid - off] : 0;
    __syncthreads();
    if (tid < 128) exo[tid] += u;
    __syncthreads();
  }
  const int base = bbase[b];
  if (tid < 128) {
    const int ex = exo[tid] - hist[tid];
    cur[tid] = ex;
    const int node = b * 128 + tid;
    if (node < N_NODES) offsets[node] = base + ex;
  }
  __syncthreads();

#pragma unroll 1
  for (int rep = 0; rep < 4; ++rep) {
    const int c = scnt[rep];
    for (int i = tid; i < c; i += 256) {
      const unsigned p = bp[rep * CAP_R + i];
      const int r = atomicAdd(&cur[p >> 16], 1);
      ssorted[base + r] = (int)(p & 0xFFFFu);
    }
  }
}

// ---------------------------------------------------------------------------
// Aggregation: one wave per dst node, online softmax, readlane broadcasts,
// paired bf16 column loads, 8 edges in flight. No atomics. (R8, unchanged.)
// ---------------------------------------------------------------------------
__global__ __launch_bounds__(256) void gat_agg(
    const __hip_bfloat16* __restrict__ zb, const float* __restrict__ asrc,
    const float* __restrict__ adst, const int* __restrict__ offsets,
    const int* __restrict__ ssorted, float* __restrict__ out) {
  const int lane = threadIdx.x & 63;
  const int cl = lane & 31;
  const int half = lane >> 5;
  const int node = (blockIdx.x * blockDim.x + threadIdx.x) >> 6;
  if (node >= N_NODES) return;
  const unsigned* __restrict__ zp = (const unsigned*)zb;
  const int o0 = offsets[node];
  const int o1 = offsets[node + 1];
  if (o0 == o1) {
    if (half == 0)
      *(float2*)(out + (size_t)node * OUT_DIM + 2 * cl) = make_float2(0.f, 0.f);
    return;
  }
  const float ad = adst[node];

  float m = NEG_INF, dsum = 0.f;
  float2 acc0 = {0.f, 0.f}, acc1 = {0.f, 0.f};
  float2 acc2 = {0.f, 0.f}, acc3 = {0.f, 0.f};

  for (int base = o0; base < o1; base += 64) {
    const int cnt = min(64, o1 - base);
    int s = 0;
    float ev = NEG_INF;
    if (lane < cnt) {
      s = ssorted[base + lane];
      float v = asrc[s] + ad;
      ev = v > 0.f ? v : NEG_SLOPE * v;
    }
    float cm = ev;
#pragma unroll
    for (int off = 32; off; off >>= 1) cm = fmaxf(cm, __shfl_xor(cm, off, 64));
    const float nm = fmaxf(m, cm);
    const float scale = __expf(m - nm);
    dsum *= scale;
    acc0.x *= scale; acc0.y *= scale; acc1.x *= scale; acc1.y *= scale;
    acc2.x *= scale; acc2.y *= scale; acc3.x *= scale; acc3.y *= scale;
    m = nm;

    float w = (lane < cnt) ? __expf(ev - m) : 0.f;
    dsum += w;

    for (int i = 0; i < cnt; i += 8) {
      int sa, sb; float wa, wb;
      sa = rlanei(s, i + 0); sb = rlanei(s, i + 1);
      wa = rlanef(w, i + 0); wb = rlanef(w, i + 1);
      const int s0 = half ? sb : sa; const float w0 = half ? wb : wa;
      sa = rlanei(s, i + 2); sb = rlanei(s, i + 3);
      wa = rlanef(w, i + 2); wb = rlanef(w, i + 3);
      const int s1 = half ? sb : sa; const float w1 = half ? wb : wa;
      sa = rlanei(s, i + 4); sb = rlanei(s, i + 5);
      wa = rlanef(w, i + 4); wb = rlanef(w, i + 5);
      const int s2 = half ? sb : sa; const float w2 = half ? wb : wa;
      sa = rlanei(s, i + 6); sb = rlanei(s, i + 7);
      wa = rlanef(w, i + 6); wb = rlanef(w, i + 7);
      const int s3 = half ? sb : sa; const float w3 = half ? wb : wa;

      const unsigned u0 = zp[(size_t)s0 * 32 + cl];
      const unsigned u1 = zp[(size_t)s1 * 32 + cl];
      const unsigned u2 = zp[(size_t)s2 * 32 + cl];
      const unsigned u3 = zp[(size_t)s3 * 32 + cl];

      acc0.x = fmaf(w0, __uint_as_float(u0 << 16), acc0.x);
      acc0.y = fmaf(w0, __uint_as_float(u0 & 0xffff0000u), acc0.y);
      acc1.x = fmaf(w1, __uint_as_float(u1 << 16), acc1.x);
      acc1.y = fmaf(w1, __uint_as_float(u1 & 0xffff0000u), acc1.y);
      acc2.x = fmaf(w2, __uint_as_float(u2 << 16), acc2.x);
      acc2.y = fmaf(w2, __uint_as_float(u2 & 0xffff0000u), acc2.y);
      acc3.x = fmaf(w3, __uint_as_float(u3 << 16), acc3.x);
      acc3.y = fmaf(w3, __uint_as_float(u3 & 0xffff0000u), acc3.y);
    }
  }
  float ax = (acc0.x + acc1.x) + (acc2.x + acc3.x);
  float ay = (acc0.y + acc1.y) + (acc2.y + acc3.y);
  ax += __shfl_xor(ax, 32, 64);
  ay += __shfl_xor(ay, 32, 64);
#pragma unroll
  for (int off = 32; off; off >>= 1) dsum += __shfl_xor(dsum, off, 64);

  const float inv = 1.f / (dsum > 0.f ? dsum : 1.f);
  float hx = ax * inv, hy = ay * inv;
  hx = hx > 0.f ? hx : expm1f(hx);
  hy = hy > 0.f ? hy : expm1f(hy);
  if (half == 0)
    *(float2*)(out + (size_t)node * OUT_DIM + 2 * cl) = make_float2(hx, hy);
}

// ---------------------------------------------------------------------------
extern "C" void kernel_launch(void* const* d_in, const int* in_sizes, int n_in,
                              void* d_out, int out_size, void* d_ws, size_t ws_size,
                              hipStream_t stream) {
  const float* feat  = (const float*)d_in[0];
  const float* fcw   = (const float*)d_in[1];
  const float* attnw = (const float*)d_in[2];
  const int* src     = (const int*)d_in[3];
  const int* dst     = (const int*)d_in[4];
  float* out = (float*)d_out;

  char* ws = (char*)d_ws;
  __hip_bfloat16* z = (__hip_bfloat16*)ws;
  ws += (size_t)N_NODES * OUT_DIM * sizeof(__hip_bfloat16);  // 6.4 MB
  float* asrc = (float*)ws;   ws += (size_t)N_NODES * sizeof(float);
  float* adst = (float*)ws;   ws += (size_t)N_NODES * sizeof(float);
  int* cnt = (int*)ws;        ws += (size_t)NB * 4 * CNT_STRIDE * sizeof(int);  // 100 KB
  int* bbase = (int*)ws;      ws += (size_t)512 * sizeof(int);
  int* offsets = (int*)ws;    ws += (size_t)(N_NODES + 4) * sizeof(int);
  unsigned* pairs = (unsigned*)ws; ws += (size_t)NB * CAP_B * sizeof(unsigned);  // 4.8 MB
  int* ssorted = (int*)ws;    ws += (size_t)N_EDGES * sizeof(int);               // 3.2 MB

  hipMemsetAsync(cnt, 0, (size_t)NB * 4 * CNT_STRIDE * sizeof(int), stream);

  gat_z_bucket<<<Z_BLOCKS + EDGE_BLOCKS, 256, 0, stream>>>(
      feat, fcw, attnw, z, asrc, adst, src, dst, cnt, pairs);
  gat_bucket_scan<<<1, 512, 0, stream>>>(cnt, bbase, offsets);
  gat_build_csr<<<NB, 256, 0, stream>>>(pairs, cnt, bbase, offsets, ssorted);
  gat_agg<<<(N_NODES * 64 + 255) / 256, 256, 0, stream>>>(z, asrc, adst,
                                                          offsets, ssorted, out);
}

// Round 10
// 147.936 us; speedup vs baseline: 1.2162x; 1.2162x over previous
//
#include <hip/hip_runtime.h>
#include <hip/hip_bf16.h>

#define N_NODES 50000
#define N_EDGES 800000
#define IN_DIM 128
#define OUT_DIM 64
#define NEG_SLOPE 0.01f
#define NEG_INF (-3.0e38f)

#define N_STRIPS (N_NODES / 16)       // 3125 16-node MFMA strips
#define Z_BLOCKS ((N_STRIPS + 3) / 4) // 782 (4 waves/block, 1 strip/wave)
#define E_I4 (N_EDGES / 4)            // 200000 int4 edge groups

// bucket sort: 128 nodes/bucket; block-local count -> reserve -> place
#define NB ((N_NODES + 127) / 128)    // 391 buckets
#define CAP_B 3072                     // slab capacity (mean occupancy 2046)
#define CNT_STRIDE 16                  // 64B line per bucket cursor
#define EB 100                         // edge blocks
#define CHUNK_I4 (E_I4 / EB)           // 2000 int4 = 8000 edges per block

typedef __bf16 bf16x8 __attribute__((ext_vector_type(8)));
typedef float f32x4 __attribute__((ext_vector_type(4)));

__device__ __forceinline__ float rlanef(float v, int l) {
  return __uint_as_float(__builtin_amdgcn_readlane(__float_as_uint(v), l));
}
__device__ __forceinline__ int rlanei(int v, int l) {
  return __builtin_amdgcn_readlane(v, l);
}

__device__ __forceinline__ unsigned short f2bf_us(float f) {
  __hip_bfloat16 h = __float2bfloat16(f);  // RNE
  return *reinterpret_cast<unsigned short*>(&h);
}
__device__ __forceinline__ bf16x8 pack_bf16(float4 lo, float4 hi) {
  union { bf16x8 v; unsigned short u[8]; } r;
  r.u[0] = f2bf_us(lo.x); r.u[1] = f2bf_us(lo.y);
  r.u[2] = f2bf_us(lo.z); r.u[3] = f2bf_us(lo.w);
  r.u[4] = f2bf_us(hi.x); r.u[5] = f2bf_us(hi.y);
  r.u[6] = f2bf_us(hi.z); r.u[7] = f2bf_us(hi.w);
  return r.v;
}

// ---------------------------------------------------------------------------
// Stage 1 (fused). Blocks [0, Z_BLOCKS): MFMA z-GEMM (R7 structure).
// Blocks [Z_BLOCKS,...): bucket pass, NO per-edge global atomics:
//   phase 1: LDS histogram of dst buckets over this block's 8K-edge chunk
//   phase 2: one global atomicAdd per (block,bucket) reserves slab space
//            (39.1K atomics total ~ 2.5us at measured 16 G/s)
//   phase 3: LDS-cursor placement, plain global stores (contiguous per
//            (block,bucket) range -> full-line L2 writes)
// ---------------------------------------------------------------------------
__global__ __launch_bounds__(256) void gat_z_bucket(
    const float* __restrict__ feat, const float* __restrict__ fcw,
    const float* __restrict__ attnw, __hip_bfloat16* __restrict__ z,
    float* __restrict__ asrc, float* __restrict__ adst,
    const int* __restrict__ src, const int* __restrict__ dst,
    int* __restrict__ cnt, unsigned* __restrict__ pairs) {
  if (blockIdx.x >= Z_BLOCKS) {
    __shared__ int hist[NB];
    __shared__ int curs[NB];
    const int tid = threadIdx.x;
    const int i0 = (blockIdx.x - Z_BLOCKS) * CHUNK_I4;
    for (int i = tid; i < NB; i += 256) hist[i] = 0;
    __syncthreads();
    // phase 1: count
    for (int t = i0 + tid; t < i0 + CHUNK_I4; t += 256) {
      int4 d = ((const int4*)dst)[t];
      atomicAdd(&hist[d.x >> 7], 1);
      atomicAdd(&hist[d.y >> 7], 1);
      atomicAdd(&hist[d.z >> 7], 1);
      atomicAdd(&hist[d.w >> 7], 1);
    }
    __syncthreads();
    // phase 2: reserve
    for (int i = tid; i < NB; i += 256) {
      int h = hist[i];
      curs[i] = h ? atomicAdd(cnt + i * CNT_STRIDE, h) : 0;
    }
    __syncthreads();
    // phase 3: place
    for (int t = i0 + tid; t < i0 + CHUNK_I4; t += 256) {
      int4 s = ((const int4*)src)[t];
      int4 d = ((const int4*)dst)[t];
#define BKT_PUT(dd, ss)                                                    \
  {                                                                        \
    int b = (dd) >> 7;                                                     \
    int r = atomicAdd(&curs[b], 1);                                        \
    if (r < CAP_B)                                                         \
      pairs[(size_t)b * CAP_B + r] =                                       \
          ((unsigned)((dd) & 127) << 16) | (unsigned)(ss);                 \
  }
      BKT_PUT(d.x, s.x)
      BKT_PUT(d.y, s.y)
      BKT_PUT(d.z, s.z)
      BKT_PUT(d.w, s.w)
#undef BKT_PUT
    }
    return;
  }

  const int lane = threadIdx.x & 63;
  const int m = lane & 15;
  const int quad = lane >> 4;
  const int wv = blockIdx.x * 4 + (threadIdx.x >> 6);
  if (wv >= N_STRIPS) return;
  const int n0 = wv * 16;

  bf16x8 bfrag[4][4];
#pragma unroll
  for (int t = 0; t < 4; ++t) {
    const float* wr = fcw + (size_t)(m + 16 * t) * IN_DIM + quad * 8;
#pragma unroll
    for (int c = 0; c < 4; ++c) {
      float4 lo = *(const float4*)(wr + c * 32);
      float4 hi = *(const float4*)(wr + c * 32 + 4);
      bfrag[t][c] = pack_bf16(lo, hi);
    }
  }

  f32x4 acc[4] = {{0.f, 0.f, 0.f, 0.f}, {0.f, 0.f, 0.f, 0.f},
                  {0.f, 0.f, 0.f, 0.f}, {0.f, 0.f, 0.f, 0.f}};
  const float* ar = feat + (size_t)(n0 + m) * IN_DIM + quad * 8;
#pragma unroll
  for (int c = 0; c < 4; ++c) {
    float4 lo = *(const float4*)(ar + c * 32);
    float4 hi = *(const float4*)(ar + c * 32 + 4);
    const bf16x8 af = pack_bf16(lo, hi);
#pragma unroll
    for (int t = 0; t < 4; ++t)
      acc[t] = __builtin_amdgcn_mfma_f32_16x16x32_bf16(af, bfrag[t][c],
                                                       acc[t], 0, 0, 0);
  }

#pragma unroll
  for (int t = 0; t < 4; ++t)
#pragma unroll
    for (int r = 0; r < 4; ++r)
      z[(size_t)(n0 + quad * 4 + r) * OUT_DIM + m + 16 * t] =
          __float2bfloat16(acc[t][r]);

  float aws[4], awd[4];
#pragma unroll
  for (int t = 0; t < 4; ++t) {
    aws[t] = attnw[m + 16 * t];
    awd[t] = attnw[OUT_DIM + m + 16 * t];
  }
  float ps[4], pd[4];
#pragma unroll
  for (int r = 0; r < 4; ++r) {
    float s = 0.f, d = 0.f;
#pragma unroll
    for (int t = 0; t < 4; ++t) {
      s = fmaf(acc[t][r], aws[t], s);
      d = fmaf(acc[t][r], awd[t], d);
    }
    ps[r] = s;
    pd[r] = d;
  }
#pragma unroll
  for (int off = 1; off < 16; off <<= 1) {
#pragma unroll
    for (int r = 0; r < 4; ++r) {
      ps[r] += __shfl_xor(ps[r], off, 64);
      pd[r] += __shfl_xor(pd[r], off, 64);
    }
  }
  if (m == 0) {
#pragma unroll
    for (int r = 0; r < 4; ++r) {
      asrc[n0 + quad * 4 + r] = ps[r];
      adst[n0 + quad * 4 + r] = pd[r];
    }
  }
}

// ---------------------------------------------------------------------------
// Exclusive scan of 391 bucket totals (one block). Writes sentinel.
// ---------------------------------------------------------------------------
__global__ __launch_bounds__(512) void gat_bucket_scan(
    const int* __restrict__ cnt, int* __restrict__ bbase,
    int* __restrict__ offsets) {
  __shared__ int ps[512];
  const int t = threadIdx.x;
  int tot = (t < NB) ? cnt[t * CNT_STRIDE] : 0;
  ps[t] = tot;
  __syncthreads();
  for (int off = 1; off < 512; off <<= 1) {
    int u = (t >= off) ? ps[t - off] : 0;
    __syncthreads();
    ps[t] += u;
    __syncthreads();
  }
  if (t < NB) bbase[t] = ps[t] - tot;  // exclusive
  if (t == NB - 1) offsets[N_NODES] = ps[t];  // == N_EDGES
}

// ---------------------------------------------------------------------------
// Per-bucket CSR build: LDS hist over 128 local bins -> LDS scan -> offsets
// + contiguous placement of src into ssorted. No global atomics.
// ---------------------------------------------------------------------------
__global__ __launch_bounds__(256) void gat_build_csr(
    const unsigned* __restrict__ pairs, const int* __restrict__ cnt,
    const int* __restrict__ bbase, int* __restrict__ offsets,
    int* __restrict__ ssorted) {
  __shared__ int hist[128], exo[128], cur[128];
  const int b = blockIdx.x;
  const int tid = threadIdx.x;
  if (tid < 128) hist[tid] = 0;
  __syncthreads();

  const int c = min(cnt[b * CNT_STRIDE], CAP_B);
  const unsigned* bp = pairs + (size_t)b * CAP_B;
  for (int i = tid; i < c; i += 256) atomicAdd(&hist[bp[i] >> 16], 1);
  __syncthreads();

  if (tid < 128) exo[tid] = hist[tid];
  __syncthreads();
  for (int off = 1; off < 128; off <<= 1) {
    int u = (tid >= off && tid < 128) ? exo[tid - off] : 0;
    __syncthreads();
    if (tid < 128) exo[tid] += u;
    __syncthreads();
  }
  const int base = bbase[b];
  if (tid < 128) {
    const int ex = exo[tid] - hist[tid];
    cur[tid] = ex;
    const int node = b * 128 + tid;
    if (node < N_NODES) offsets[node] = base + ex;
  }
  __syncthreads();

  for (int i = tid; i < c; i += 256) {
    const unsigned p = bp[i];
    const int r = atomicAdd(&cur[p >> 16], 1);
    ssorted[base + r] = (int)(p & 0xFFFFu);
  }
}

// ---------------------------------------------------------------------------
// Aggregation: one wave per dst node, online softmax, readlane broadcasts,
// paired bf16 column loads, 8 edges in flight. No atomics. (R8, unchanged.)
// ---------------------------------------------------------------------------
__global__ __launch_bounds__(256) void gat_agg(
    const __hip_bfloat16* __restrict__ zb, const float* __restrict__ asrc,
    const float* __restrict__ adst, const int* __restrict__ offsets,
    const int* __restrict__ ssorted, float* __restrict__ out) {
  const int lane = threadIdx.x & 63;
  const int cl = lane & 31;
  const int half = lane >> 5;
  const int node = (blockIdx.x * blockDim.x + threadIdx.x) >> 6;
  if (node >= N_NODES) return;
  const unsigned* __restrict__ zp = (const unsigned*)zb;
  const int o0 = offsets[node];
  const int o1 = offsets[node + 1];
  if (o0 == o1) {
    if (half == 0)
      *(float2*)(out + (size_t)node * OUT_DIM + 2 * cl) = make_float2(0.f, 0.f);
    return;
  }
  const float ad = adst[node];

  float m = NEG_INF, dsum = 0.f;
  float2 acc0 = {0.f, 0.f}, acc1 = {0.f, 0.f};
  float2 acc2 = {0.f, 0.f}, acc3 = {0.f, 0.f};

  for (int base = o0; base < o1; base += 64) {
    const int cnt = min(64, o1 - base);
    int s = 0;
    float ev = NEG_INF;
    if (lane < cnt) {
      s = ssorted[base + lane];
      float v = asrc[s] + ad;
      ev = v > 0.f ? v : NEG_SLOPE * v;
    }
    float cm = ev;
#pragma unroll
    for (int off = 32; off; off >>= 1) cm = fmaxf(cm, __shfl_xor(cm, off, 64));
    const float nm = fmaxf(m, cm);
    const float scale = __expf(m - nm);
    dsum *= scale;
    acc0.x *= scale; acc0.y *= scale; acc1.x *= scale; acc1.y *= scale;
    acc2.x *= scale; acc2.y *= scale; acc3.x *= scale; acc3.y *= scale;
    m = nm;

    float w = (lane < cnt) ? __expf(ev - m) : 0.f;
    dsum += w;

    for (int i = 0; i < cnt; i += 8) {
      int sa, sb; float wa, wb;
      sa = rlanei(s, i + 0); sb = rlanei(s, i + 1);
      wa = rlanef(w, i + 0); wb = rlanef(w, i + 1);
      const int s0 = half ? sb : sa; const float w0 = half ? wb : wa;
      sa = rlanei(s, i + 2); sb = rlanei(s, i + 3);
      wa = rlanef(w, i + 2); wb = rlanef(w, i + 3);
      const int s1 = half ? sb : sa; const float w1 = half ? wb : wa;
      sa = rlanei(s, i + 4); sb = rlanei(s, i + 5);
      wa = rlanef(w, i + 4); wb = rlanef(w, i + 5);
      const int s2 = half ? sb : sa; const float w2 = half ? wb : wa;
      sa = rlanei(s, i + 6); sb = rlanei(s, i + 7);
      wa = rlanef(w, i + 6); wb = rlanef(w, i + 7);
      const int s3 = half ? sb : sa; const float w3 = half ? wb : wa;

      const unsigned u0 = zp[(size_t)s0 * 32 + cl];
      const unsigned u1 = zp[(size_t)s1 * 32 + cl];
      const unsigned u2 = zp[(size_t)s2 * 32 + cl];
      const unsigned u3 = zp[(size_t)s3 * 32 + cl];

      acc0.x = fmaf(w0, __uint_as_float(u0 << 16), acc0.x);
      acc0.y = fmaf(w0, __uint_as_float(u0 & 0xffff0000u), acc0.y);
      acc1.x = fmaf(w1, __uint_as_float(u1 << 16), acc1.x);
      acc1.y = fmaf(w1, __uint_as_float(u1 & 0xffff0000u), acc1.y);
      acc2.x = fmaf(w2, __uint_as_float(u2 << 16), acc2.x);
      acc2.y = fmaf(w2, __uint_as_float(u2 & 0xffff0000u), acc2.y);
      acc3.x = fmaf(w3, __uint_as_float(u3 << 16), acc3.x);
      acc3.y = fmaf(w3, __uint_as_float(u3 & 0xffff0000u), acc3.y);
    }
  }
  float ax = (acc0.x + acc1.x) + (acc2.x + acc3.x);
  float ay = (acc0.y + acc1.y) + (acc2.y + acc3.y);
  ax += __shfl_xor(ax, 32, 64);
  ay += __shfl_xor(ay, 32, 64);
#pragma unroll
  for (int off = 32; off; off >>= 1) dsum += __shfl_xor(dsum, off, 64);

  const float inv = 1.f / (dsum > 0.f ? dsum : 1.f);
  float hx = ax * inv, hy = ay * inv;
  hx = hx > 0.f ? hx : expm1f(hx);
  hy = hy > 0.f ? hy : expm1f(hy);
  if (half == 0)
    *(float2*)(out + (size_t)node * OUT_DIM + 2 * cl) = make_float2(hx, hy);
}

// ---------------------------------------------------------------------------
extern "C" void kernel_launch(void* const* d_in, const int* in_sizes, int n_in,
                              void* d_out, int out_size, void* d_ws, size_t ws_size,
                              hipStream_t stream) {
  const float* feat  = (const float*)d_in[0];
  const float* fcw   = (const float*)d_in[1];
  const float* attnw = (const float*)d_in[2];
  const int* src     = (const int*)d_in[3];
  const int* dst     = (const int*)d_in[4];
  float* out = (float*)d_out;

  char* ws = (char*)d_ws;
  __hip_bfloat16* z = (__hip_bfloat16*)ws;
  ws += (size_t)N_NODES * OUT_DIM * sizeof(__hip_bfloat16);  // 6.4 MB
  float* asrc = (float*)ws;   ws += (size_t)N_NODES * sizeof(float);
  float* adst = (float*)ws;   ws += (size_t)N_NODES * sizeof(float);
  int* cnt = (int*)ws;        ws += (size_t)NB * CNT_STRIDE * sizeof(int);  // 25 KB
  int* bbase = (int*)ws;      ws += (size_t)512 * sizeof(int);
  int* offsets = (int*)ws;    ws += (size_t)(N_NODES + 4) * sizeof(int);
  unsigned* pairs = (unsigned*)ws; ws += (size_t)NB * CAP_B * sizeof(unsigned);  // 4.8 MB
  int* ssorted = (int*)ws;    ws += (size_t)N_EDGES * sizeof(int);               // 3.2 MB

  hipMemsetAsync(cnt, 0, (size_t)NB * CNT_STRIDE * sizeof(int), stream);

  gat_z_bucket<<<Z_BLOCKS + EB, 256, 0, stream>>>(
      feat, fcw, attnw, z, asrc, adst, src, dst, cnt, pairs);
  gat_bucket_scan<<<1, 512, 0, stream>>>(cnt, bbase, offsets);
  gat_build_csr<<<NB, 256, 0, stream>>>(pairs, cnt, bbase, offsets, ssorted);
  gat_agg<<<(N_NODES * 64 + 255) / 256, 256, 0, stream>>>(z, asrc, adst,
                                                          offsets, ssorted, out);
}

// Round 11
// 145.818 us; speedup vs baseline: 1.2339x; 1.0145x over previous
//
#include <hip/hip_runtime.h>
#include <hip/hip_bf16.h>
#include <hip/hip_fp16.h>

#define N_NODES 50000
#define N_EDGES 800000
#define IN_DIM 128
#define OUT_DIM 64
#define NEG_SLOPE 0.01f
#define NEG_INF (-3.0e38f)

#define N_STRIPS (N_NODES / 16)       // 3125 16-node MFMA strips
#define Z_BLOCKS ((N_STRIPS + 3) / 4) // 782 (4 waves/block, 1 strip/wave)
#define E_I4 (N_EDGES / 4)            // 200000 int4 edge groups

// bucket sort: 128 nodes/bucket; block-local count -> reserve -> place
#define NB ((N_NODES + 127) / 128)    // 391 buckets
#define CAP_B 3072                     // slab capacity (mean occupancy 2046)
#define CNT_STRIDE 16                  // 64B line per bucket cursor
#define EB 100                         // edge blocks
#define CHUNK_I4 (E_I4 / EB)           // 2000 int4 = 8000 edges per block

typedef __bf16 bf16x8 __attribute__((ext_vector_type(8)));
typedef float f32x4 __attribute__((ext_vector_type(4)));

__device__ __forceinline__ unsigned short f2bf_us(float f) {
  __hip_bfloat16 h = __float2bfloat16(f);  // RNE
  return *reinterpret_cast<unsigned short*>(&h);
}
__device__ __forceinline__ bf16x8 pack_bf16(float4 lo, float4 hi) {
  union { bf16x8 v; unsigned short u[8]; } r;
  r.u[0] = f2bf_us(lo.x); r.u[1] = f2bf_us(lo.y);
  r.u[2] = f2bf_us(lo.z); r.u[3] = f2bf_us(lo.w);
  r.u[4] = f2bf_us(hi.x); r.u[5] = f2bf_us(hi.y);
  r.u[6] = f2bf_us(hi.z); r.u[7] = f2bf_us(hi.w);
  return r.v;
}
__device__ __forceinline__ float bflo(unsigned u) {
  return __uint_as_float(u << 16);
}
__device__ __forceinline__ float bfhi(unsigned u) {
  return __uint_as_float(u & 0xffff0000u);
}

// ---------------------------------------------------------------------------
// Stage 1 (fused). Blocks [0, Z_BLOCKS): MFMA z-GEMM (R7 structure).
// Blocks [Z_BLOCKS,...): bucket pass (R10 structure, no per-edge global
// atomics: LDS count -> one reserve atomic per (block,bucket) -> place).
// ---------------------------------------------------------------------------
__global__ __launch_bounds__(256) void gat_z_bucket(
    const float* __restrict__ feat, const float* __restrict__ fcw,
    const float* __restrict__ attnw, __hip_bfloat16* __restrict__ z,
    float* __restrict__ asrc, float* __restrict__ adst,
    const int* __restrict__ src, const int* __restrict__ dst,
    int* __restrict__ cnt, unsigned* __restrict__ pairs) {
  if (blockIdx.x >= Z_BLOCKS) {
    __shared__ int hist[NB];
    __shared__ int curs[NB];
    const int tid = threadIdx.x;
    const int i0 = (blockIdx.x - Z_BLOCKS) * CHUNK_I4;
    for (int i = tid; i < NB; i += 256) hist[i] = 0;
    __syncthreads();
    for (int t = i0 + tid; t < i0 + CHUNK_I4; t += 256) {
      int4 d = ((const int4*)dst)[t];
      atomicAdd(&hist[d.x >> 7], 1);
      atomicAdd(&hist[d.y >> 7], 1);
      atomicAdd(&hist[d.z >> 7], 1);
      atomicAdd(&hist[d.w >> 7], 1);
    }
    __syncthreads();
    for (int i = tid; i < NB; i += 256) {
      int h = hist[i];
      curs[i] = h ? atomicAdd(cnt + i * CNT_STRIDE, h) : 0;
    }
    __syncthreads();
    for (int t = i0 + tid; t < i0 + CHUNK_I4; t += 256) {
      int4 s = ((const int4*)src)[t];
      int4 d = ((const int4*)dst)[t];
#define BKT_PUT(dd, ss)                                                    \
  {                                                                        \
    int b = (dd) >> 7;                                                     \
    int r = atomicAdd(&curs[b], 1);                                        \
    if (r < CAP_B)                                                         \
      pairs[(size_t)b * CAP_B + r] =                                       \
          ((unsigned)((dd) & 127) << 16) | (unsigned)(ss);                 \
  }
      BKT_PUT(d.x, s.x)
      BKT_PUT(d.y, s.y)
      BKT_PUT(d.z, s.z)
      BKT_PUT(d.w, s.w)
#undef BKT_PUT
    }
    return;
  }

  const int lane = threadIdx.x & 63;
  const int m = lane & 15;
  const int quad = lane >> 4;
  const int wv = blockIdx.x * 4 + (threadIdx.x >> 6);
  if (wv >= N_STRIPS) return;
  const int n0 = wv * 16;

  bf16x8 bfrag[4][4];
#pragma unroll
  for (int t = 0; t < 4; ++t) {
    const float* wr = fcw + (size_t)(m + 16 * t) * IN_DIM + quad * 8;
#pragma unroll
    for (int c = 0; c < 4; ++c) {
      float4 lo = *(const float4*)(wr + c * 32);
      float4 hi = *(const float4*)(wr + c * 32 + 4);
      bfrag[t][c] = pack_bf16(lo, hi);
    }
  }

  f32x4 acc[4] = {{0.f, 0.f, 0.f, 0.f}, {0.f, 0.f, 0.f, 0.f},
                  {0.f, 0.f, 0.f, 0.f}, {0.f, 0.f, 0.f, 0.f}};
  const float* ar = feat + (size_t)(n0 + m) * IN_DIM + quad * 8;
#pragma unroll
  for (int c = 0; c < 4; ++c) {
    float4 lo = *(const float4*)(ar + c * 32);
    float4 hi = *(const float4*)(ar + c * 32 + 4);
    const bf16x8 af = pack_bf16(lo, hi);
#pragma unroll
    for (int t = 0; t < 4; ++t)
      acc[t] = __builtin_amdgcn_mfma_f32_16x16x32_bf16(af, bfrag[t][c],
                                                       acc[t], 0, 0, 0);
  }

#pragma unroll
  for (int t = 0; t < 4; ++t)
#pragma unroll
    for (int r = 0; r < 4; ++r)
      z[(size_t)(n0 + quad * 4 + r) * OUT_DIM + m + 16 * t] =
          __float2bfloat16(acc[t][r]);

  float aws[4], awd[4];
#pragma unroll
  for (int t = 0; t < 4; ++t) {
    aws[t] = attnw[m + 16 * t];
    awd[t] = attnw[OUT_DIM + m + 16 * t];
  }
  float ps[4], pd[4];
#pragma unroll
  for (int r = 0; r < 4; ++r) {
    float s = 0.f, d = 0.f;
#pragma unroll
    for (int t = 0; t < 4; ++t) {
      s = fmaf(acc[t][r], aws[t], s);
      d = fmaf(acc[t][r], awd[t], d);
    }
    ps[r] = s;
    pd[r] = d;
  }
#pragma unroll
  for (int off = 1; off < 16; off <<= 1) {
#pragma unroll
    for (int r = 0; r < 4; ++r) {
      ps[r] += __shfl_xor(ps[r], off, 64);
      pd[r] += __shfl_xor(pd[r], off, 64);
    }
  }
  if (m == 0) {
#pragma unroll
    for (int r = 0; r < 4; ++r) {
      asrc[n0 + quad * 4 + r] = ps[r];
      adst[n0 + quad * 4 + r] = pd[r];
    }
  }
}

// ---------------------------------------------------------------------------
// Per-bucket CSR build. Computes its own global base (sum of cnt[0..b),
// L2-hot, ~2 loads/thread) — the separate bucket_scan kernel is gone.
// ---------------------------------------------------------------------------
__global__ __launch_bounds__(256) void gat_build_csr(
    const unsigned* __restrict__ pairs, const int* __restrict__ cnt,
    int* __restrict__ offsets, int* __restrict__ ssorted) {
  __shared__ int hist[128], exo[128], cur[128], wsum[4];
  const int b = blockIdx.x;
  const int tid = threadIdx.x;

  int ls = 0;
  for (int i = tid; i < b; i += 256) ls += cnt[i * CNT_STRIDE];
#pragma unroll
  for (int off = 32; off; off >>= 1) ls += __shfl_xor(ls, off, 64);
  if ((tid & 63) == 0) wsum[tid >> 6] = ls;
  if (tid < 128) hist[tid] = 0;
  __syncthreads();
  const int base = wsum[0] + wsum[1] + wsum[2] + wsum[3];

  const int c = min(cnt[b * CNT_STRIDE], CAP_B);
  const unsigned* bp = pairs + (size_t)b * CAP_B;
  for (int i = tid; i < c; i += 256) atomicAdd(&hist[bp[i] >> 16], 1);
  __syncthreads();

  if (tid < 128) exo[tid] = hist[tid];
  __syncthreads();
  for (int off = 1; off < 128; off <<= 1) {
    int u = (tid >= off && tid < 128) ? exo[tid - off] : 0;
    __syncthreads();
    if (tid < 128) exo[tid] += u;
    __syncthreads();
  }
  if (tid < 128) {
    const int ex = exo[tid] - hist[tid];
    cur[tid] = ex;
    const int node = b * 128 + tid;
    if (node < N_NODES) offsets[node] = base + ex;
  }
  if (b == NB - 1 && tid == 0) offsets[N_NODES] = base + c;
  __syncthreads();

  for (int i = tid; i < c; i += 256) {
    const unsigned p = bp[i];
    const int r = atomicAdd(&cur[p >> 16], 1);
    ssorted[base + r] = (int)(p & 0xFFFFu);
  }
}

// ---------------------------------------------------------------------------
// Aggregation: one wave per dst node, online softmax. Gather phase: lane =
// (edge-subgroup eg=lane>>3, col-quad j=lane&7); per 8 edges one bpermute
// (s | f16(w)<<16 packed) + one uint4 load (8 bf16 cols) + 8 FMAs. Two
// accumulator banks for ILP; 3-step shfl_xor cross-subgroup reduction.
// ---------------------------------------------------------------------------
__global__ __launch_bounds__(256) void gat_agg(
    const __hip_bfloat16* __restrict__ zb, const float* __restrict__ asrc,
    const float* __restrict__ adst, const int* __restrict__ offsets,
    const int* __restrict__ ssorted, float* __restrict__ out) {
  const int lane = threadIdx.x & 63;
  const int j = lane & 7;    // column quad: cols 8j..8j+7
  const int eg = lane >> 3;  // edge subgroup 0..7
  const int node = (blockIdx.x * blockDim.x + threadIdx.x) >> 6;
  if (node >= N_NODES) return;
  const uint4* __restrict__ zp4 = (const uint4*)zb;  // 8 uint4 per 64-col row
  const int o0 = offsets[node];
  const int o1 = offsets[node + 1];
  float4* __restrict__ orow = (float4*)(out + (size_t)node * OUT_DIM);
  if (o0 == o1) {  // no incoming edges: elu(0/1) = 0
    if (eg == 0) {
      const float4 zv = {0.f, 0.f, 0.f, 0.f};
      orow[2 * j] = zv;
      orow[2 * j + 1] = zv;
    }
    return;
  }
  const float ad = adst[node];

  float m = NEG_INF, dsum = 0.f;
  float acca[8] = {0.f, 0.f, 0.f, 0.f, 0.f, 0.f, 0.f, 0.f};
  float accb[8] = {0.f, 0.f, 0.f, 0.f, 0.f, 0.f, 0.f, 0.f};

  for (int base = o0; base < o1; base += 64) {
    const int cnt = min(64, o1 - base);
    int s = 0;
    float ev = NEG_INF;
    if (lane < cnt) {
      s = ssorted[base + lane];
      float v = asrc[s] + ad;
      ev = v > 0.f ? v : NEG_SLOPE * v;
    }
    float cm = ev;
#pragma unroll
    for (int off = 32; off; off >>= 1) cm = fmaxf(cm, __shfl_xor(cm, off, 64));
    const float nm = fmaxf(m, cm);
    const float scale = __expf(m - nm);  // first chunk: exp(-inf) = 0
    dsum *= scale;
#pragma unroll
    for (int c = 0; c < 8; ++c) {
      acca[c] *= scale;
      accb[c] *= scale;
    }
    m = nm;

    const float w = (lane < cnt) ? __expf(ev - m) : 0.f;  // 0 beyond cnt
    dsum += w;
    // pack s (16b) | f16(w) (16b); s=0,w=0 for idle lanes -> harmless
    const unsigned pk =
        (unsigned)s |
        ((unsigned)__half_as_ushort(__float2half(w)) << 16);

    const int ngr = (cnt + 7) >> 3;
    for (int g = 0; g < ngr; g += 2) {
      const unsigned pa = __shfl(pk, 8 * g + eg, 64);
      const int sa = (int)(pa & 0xFFFFu);
      const float wa = __half2float(__ushort_as_half((unsigned short)(pa >> 16)));
      const uint4 ua = zp4[(size_t)sa * 8 + j];
      if (g + 1 < ngr) {
        const unsigned pb = __shfl(pk, 8 * (g + 1) + eg, 64);
        const int sb = (int)(pb & 0xFFFFu);
        const float wb =
            __half2float(__ushort_as_half((unsigned short)(pb >> 16)));
        const uint4 ub = zp4[(size_t)sb * 8 + j];
        accb[0] = fmaf(wb, bflo(ub.x), accb[0]);
        accb[1] = fmaf(wb, bfhi(ub.x), accb[1]);
        accb[2] = fmaf(wb, bflo(ub.y), accb[2]);
        accb[3] = fmaf(wb, bfhi(ub.y), accb[3]);
        accb[4] = fmaf(wb, bflo(ub.z), accb[4]);
        accb[5] = fmaf(wb, bfhi(ub.z), accb[5]);
        accb[6] = fmaf(wb, bflo(ub.w), accb[6]);
        accb[7] = fmaf(wb, bfhi(ub.w), accb[7]);
      }
      acca[0] = fmaf(wa, bflo(ua.x), acca[0]);
      acca[1] = fmaf(wa, bfhi(ua.x), acca[1]);
      acca[2] = fmaf(wa, bflo(ua.y), acca[2]);
      acca[3] = fmaf(wa, bfhi(ua.y), acca[3]);
      acca[4] = fmaf(wa, bflo(ua.z), acca[4]);
      acca[5] = fmaf(wa, bfhi(ua.z), acca[5]);
      acca[6] = fmaf(wa, bflo(ua.w), acca[6]);
      acca[7] = fmaf(wa, bfhi(ua.w), acca[7]);
    }
  }

  float acc[8];
#pragma unroll
  for (int c = 0; c < 8; ++c) acc[c] = acca[c] + accb[c];
#pragma unroll
  for (int off = 8; off < 64; off <<= 1)
#pragma unroll
    for (int c = 0; c < 8; ++c) acc[c] += __shfl_xor(acc[c], off, 64);
#pragma unroll
  for (int off = 32; off; off >>= 1) dsum += __shfl_xor(dsum, off, 64);

  if (eg == 0) {
    const float inv = 1.f / (dsum > 0.f ? dsum : 1.f);
    float4 r0, r1;
    float h;
    h = acc[0] * inv; r0.x = h > 0.f ? h : expm1f(h);
    h = acc[1] * inv; r0.y = h > 0.f ? h : expm1f(h);
    h = acc[2] * inv; r0.z = h > 0.f ? h : expm1f(h);
    h = acc[3] * inv; r0.w = h > 0.f ? h : expm1f(h);
    h = acc[4] * inv; r1.x = h > 0.f ? h : expm1f(h);
    h = acc[5] * inv; r1.y = h > 0.f ? h : expm1f(h);
    h = acc[6] * inv; r1.z = h > 0.f ? h : expm1f(h);
    h = acc[7] * inv; r1.w = h > 0.f ? h : expm1f(h);
    orow[2 * j] = r0;
    orow[2 * j + 1] = r1;
  }
}

// ---------------------------------------------------------------------------
extern "C" void kernel_launch(void* const* d_in, const int* in_sizes, int n_in,
                              void* d_out, int out_size, void* d_ws, size_t ws_size,
                              hipStream_t stream) {
  const float* feat  = (const float*)d_in[0];
  const float* fcw   = (const float*)d_in[1];
  const float* attnw = (const float*)d_in[2];
  const int* src     = (const int*)d_in[3];
  const int* dst     = (const int*)d_in[4];
  float* out = (float*)d_out;

  char* ws = (char*)d_ws;
  __hip_bfloat16* z = (__hip_bfloat16*)ws;
  ws += (size_t)N_NODES * OUT_DIM * sizeof(__hip_bfloat16);  // 6.4 MB
  float* asrc = (float*)ws;   ws += (size_t)N_NODES * sizeof(float);
  float* adst = (float*)ws;   ws += (size_t)N_NODES * sizeof(float);
  int* cnt = (int*)ws;        ws += (size_t)NB * CNT_STRIDE * sizeof(int);  // 25 KB
  int* offsets = (int*)ws;    ws += (size_t)(N_NODES + 4) * sizeof(int);
  unsigned* pairs = (unsigned*)ws; ws += (size_t)NB * CAP_B * sizeof(unsigned);  // 4.8 MB
  int* ssorted = (int*)ws;    ws += (size_t)N_EDGES * sizeof(int);               // 3.2 MB

  hipMemsetAsync(cnt, 0, (size_t)NB * CNT_STRIDE * sizeof(int), stream);

  gat_z_bucket<<<Z_BLOCKS + EB, 256, 0, stream>>>(
      feat, fcw, attnw, z, asrc, adst, src, dst, cnt, pairs);
  gat_build_csr<<<NB, 256, 0, stream>>>(pairs, cnt, offsets, ssorted);
  gat_agg<<<(N_NODES * 64 + 255) / 256, 256, 0, stream>>>(z, asrc, adst,
                                                          offsets, ssorted, out);
}